// Round 3
// baseline (1154.463 us; speedup 1.0000x reference)
//
#include <hip/hip_runtime.h>
#include <hip/hip_fp16.h>

#define QLEN 1024
#define MLEN 1024
#define KLEN 2048
#define RLEN 3072
#define BB 2
#define NH 16
#define DHH 64
#define DD 1024
#define SCALE 0.125f
#define UW 2112  // padded bdr band width (needed 2111)

__device__ __forceinline__ void f4a(float4 v, float* a) {
    a[0] = v.x; a[1] = v.y; a[2] = v.z; a[3] = v.w;
}

// ---------------------------------------------------------------------------
// Pack seg_mat(one-hot diff bit) + attn_mask(0/1) into 1 byte per (i,j,b).
// flags layout: [(i*KLEN + j)*BB + b]; bit0 = diff segment, bit1 = masked.
// ---------------------------------------------------------------------------
__global__ __launch_bounds__(256) void k_pack(const float* __restrict__ seg,
                                              const float* __restrict__ msk,
                                              unsigned char* __restrict__ flags) {
    const int idx = blockIdx.x * 256 + threadIdx.x;  // 0 .. QLEN*KLEN*BB-1
    const float diff = seg[(size_t)idx * 2 + 1];
    const float mk = msk[idx];
    flags[idx] = (unsigned char)((diff > 0.5f ? 1 : 0) | (mk > 0.5f ? 2 : 0));
}

// ---------------------------------------------------------------------------
// Head projection GEMM: out[b][n][row][dh] = sum_d X[row,b,d] * W[d, n*64+dh]
// X rows: row < split -> X0[row], else X1[row-split]  (handles concat(mems,h))
// grid: (R/64, NH, BB), 256 threads, 64x64 tile, BK=32, 4x4 micro.
// ---------------------------------------------------------------------------
__global__ __launch_bounds__(256) void k_proj(const float* __restrict__ X0,
                                              const float* __restrict__ X1,
                                              const int split, const int R,
                                              const float* __restrict__ W,
                                              float* __restrict__ outp) {
    __shared__ float Xs[32][68];  // [k][row]
    __shared__ float Ws[32][68];  // [k][col]
    const int b = blockIdx.z, n = blockIdx.y;
    const int r0 = blockIdx.x * 64;
    const int t = threadIdx.x, tx = t & 15, ty = t >> 4;
    float acc[4][4] = {};
    for (int k0 = 0; k0 < DD; k0 += 32) {
        // stage X tile (transposed to k-major)
#pragma unroll
        for (int e = 0; e < 2; e++) {
            int idx = t + 256 * e;
            int row = idx >> 3, kq = idx & 7;
            int gr = r0 + row;
            const float* Xp = (gr < split) ? (X0 + (size_t)gr * (BB * DD))
                                           : (X1 + (size_t)(gr - split) * (BB * DD));
            float4 v = *(const float4*)&Xp[b * DD + k0 + kq * 4];
            Xs[kq * 4 + 0][row] = v.x;
            Xs[kq * 4 + 1][row] = v.y;
            Xs[kq * 4 + 2][row] = v.z;
            Xs[kq * 4 + 3][row] = v.w;
        }
        // stage W tile
#pragma unroll
        for (int e = 0; e < 2; e++) {
            int idx = t + 256 * e;
            int k = idx >> 4, nq = idx & 15;
            *(float4*)&Ws[k][nq * 4] =
                *(const float4*)&W[(size_t)(k0 + k) * DD + n * DHH + nq * 4];
        }
        __syncthreads();
#pragma unroll 8
        for (int kk = 0; kk < 32; kk++) {
            float xa[4], wb[4];
            f4a(*(const float4*)&Xs[kk][ty * 4], xa);
            f4a(*(const float4*)&Ws[kk][tx * 4], wb);
#pragma unroll
            for (int c = 0; c < 4; c++)
#pragma unroll
                for (int a = 0; a < 4; a++) acc[c][a] += xa[c] * wb[a];
        }
        __syncthreads();
    }
    const size_t obase = ((size_t)(b * NH + n) * R + r0) * DHH;
#pragma unroll
    for (int c = 0; c < 4; c++)
        *(float4*)&outp[obase + (size_t)(ty * 4 + c) * DHH + tx * 4] =
            make_float4(acc[c][0], acc[c][1], acc[c][2], acc[c][3]);
}

// ---------------------------------------------------------------------------
// Banded position-term GEMM:
//   bdr[bn][itile][il][u] = sum_d (q[i0+il,d]+rr_bias[n,d]) * kr[jrbase+u, d]
// with jrbase = QLEN - i0 - 63. fp16 output. grid: (16 itiles, 32 bn).
// ---------------------------------------------------------------------------
__global__ __launch_bounds__(256) void k_bdr(const float* __restrict__ qh,
                                             const float* __restrict__ krh,
                                             const float* __restrict__ rr_bias,
                                             __half* __restrict__ bdr) {
    __shared__ float qr_t[64][68];  // [d][i]
    __shared__ float kr_t[64][68];  // [d][u]
    const int itile = blockIdx.x, bn = blockIdx.y;
    const int n = bn & 15;
    const int i0 = itile * 64;
    const int t = threadIdx.x, tx = t & 15, ty = t >> 4;
#pragma unroll
    for (int e = 0; e < 4; e++) {
        int idx = t + 256 * e;
        int i = idx >> 4, dq = idx & 15;
        float4 qv = *(const float4*)&qh[((size_t)bn * QLEN + i0 + i) * DHH + dq * 4];
        float4 br = *(const float4*)&rr_bias[n * DHH + dq * 4];
        qr_t[dq * 4 + 0][i] = qv.x + br.x;
        qr_t[dq * 4 + 1][i] = qv.y + br.y;
        qr_t[dq * 4 + 2][i] = qv.z + br.z;
        qr_t[dq * 4 + 3][i] = qv.w + br.w;
    }
    const int jrbase = QLEN - i0 - 63;  // >= 1 always
    const size_t obase = ((size_t)bn * 16 + itile) * 64 * UW;
    __syncthreads();
    for (int ut = 0; ut < 33; ut++) {
        const int u0 = ut * 64;
#pragma unroll
        for (int e = 0; e < 4; e++) {
            int idx = t + 256 * e;
            int u = idx >> 4, dq = idx & 15;
            int jr = jrbase + u0 + u;
            if (jr > RLEN - 1) jr = RLEN - 1;  // only the last pad column
            float4 kv = *(const float4*)&krh[((size_t)bn * RLEN + jr) * DHH + dq * 4];
            kr_t[dq * 4 + 0][u] = kv.x;
            kr_t[dq * 4 + 1][u] = kv.y;
            kr_t[dq * 4 + 2][u] = kv.z;
            kr_t[dq * 4 + 3][u] = kv.w;
        }
        __syncthreads();
        float acc[4][4] = {};
#pragma unroll 8
        for (int d = 0; d < 64; d++) {
            float qa[4], kb[4];
            f4a(*(const float4*)&qr_t[d][ty * 4], qa);
            f4a(*(const float4*)&kr_t[d][tx * 4], kb);
#pragma unroll
            for (int c = 0; c < 4; c++)
#pragma unroll
                for (int a = 0; a < 4; a++) acc[c][a] += qa[c] * kb[a];
        }
#pragma unroll
        for (int c = 0; c < 4; c++) {
            __half2* wp = (__half2*)&bdr[obase + (size_t)(ty * 4 + c) * UW + u0 + tx * 4];
            wp[0] = __floats2half2_rn(acc[c][0], acc[c][1]);
            wp[1] = __floats2half2_rn(acc[c][2], acc[c][3]);
        }
        __syncthreads();
    }
}

// ---------------------------------------------------------------------------
// Fused scores + online softmax + PV. One block per (itile 64 rows, bn).
// score(i,j) = (qc_i . k_j  +  bdr[i][j0+jl-il+63]  +  efs[i][diffbit]) * SCALE
//              - 1e30 * maskbit
// ---------------------------------------------------------------------------
__global__ __launch_bounds__(256) void k_scorepv(
    const float* __restrict__ qh, const float* __restrict__ kh,
    const float* __restrict__ vh, const __half* __restrict__ bdr,
    const unsigned char* __restrict__ flags, const float* __restrict__ rw_bias,
    const float* __restrict__ rs_bias, const float* __restrict__ seg_embed,
    float* __restrict__ av) {
    __shared__ float qc_t[64][68];  // [d][i], q + r_w_bias
    __shared__ float ks_t[64][68];  // [d][j]
    __shared__ float vs[64][68];    // [j][dv]
    __shared__ float ps[64][68];    // scores -> probs
    __shared__ float efs[64][2];
    __shared__ float m_s[64], l_s[64], corr_s[64];

    const int itile = blockIdx.x, bn = blockIdx.y;
    const int b = bn >> 4, n = bn & 15;
    const int i0 = itile * 64;
    const int t = threadIdx.x, tx = t & 15, ty = t >> 4;

#pragma unroll
    for (int e = 0; e < 4; e++) {
        int idx = t + 256 * e;
        int i = idx >> 4, dq = idx & 15;
        float4 qv = *(const float4*)&qh[((size_t)bn * QLEN + i0 + i) * DHH + dq * 4];
        float4 bw = *(const float4*)&rw_bias[n * DHH + dq * 4];
        qc_t[dq * 4 + 0][i] = qv.x + bw.x;
        qc_t[dq * 4 + 1][i] = qv.y + bw.y;
        qc_t[dq * 4 + 2][i] = qv.z + bw.z;
        qc_t[dq * 4 + 3][i] = qv.w + bw.w;
    }
    if (t < 64) {
        m_s[t] = -3.0e38f;
        l_s[t] = 0.f;
    }
    __syncthreads();
    if (t < 128) {  // efs[i][s] = (q_raw + rs_bias) . seg_embed[s][n][:]
        int i = t >> 1, s = t & 1;
        float sum = 0.f;
        for (int d = 0; d < DHH; d++) {
            float qraw = qc_t[d][i] - rw_bias[n * DHH + d] + rs_bias[n * DHH + d];
            sum += qraw * seg_embed[(s * NH + n) * DHH + d];
        }
        efs[i][s] = sum;
    }
    __syncthreads();

    float acc[4][4] = {};
    const size_t bdbase = ((size_t)bn * 16 + itile) * 64 * UW;

    for (int jt = 0; jt < 32; jt++) {
        const int j0 = jt * 64;
#pragma unroll
        for (int e = 0; e < 4; e++) {
            int idx = t + 256 * e;
            int j = idx >> 4, dq = idx & 15;
            size_t g = ((size_t)bn * KLEN + j0 + j) * DHH + dq * 4;
            float4 kv = *(const float4*)&kh[g];
            ks_t[dq * 4 + 0][j] = kv.x;
            ks_t[dq * 4 + 1][j] = kv.y;
            ks_t[dq * 4 + 2][j] = kv.z;
            ks_t[dq * 4 + 3][j] = kv.w;
            *(float4*)&vs[j][dq * 4] = *(const float4*)&vh[g];
        }
        __syncthreads();

        float s4[4][4] = {};
#pragma unroll 8
        for (int d = 0; d < 64; d++) {
            float qa[4], kb[4];
            f4a(*(const float4*)&qc_t[d][ty * 4], qa);
            f4a(*(const float4*)&ks_t[d][tx * 4], kb);
#pragma unroll
            for (int c = 0; c < 4; c++)
#pragma unroll
                for (int a = 0; a < 4; a++) s4[c][a] += qa[c] * kb[a];
        }
        // bd + ef + mask + scale
#pragma unroll
        for (int c = 0; c < 4; c++) {
            const int il = ty * 4 + c;
            const int gi = i0 + il;
            const __half* bp = &bdr[bdbase + (size_t)il * UW + (j0 + tx * 4 + 63 - il)];
            const unsigned char* fp = &flags[((size_t)gi * KLEN + j0 + tx * 4) * BB + b];
#pragma unroll
            for (int a = 0; a < 4; a++) {
                float bd = __half2float(bp[a]);
                unsigned char f = fp[a * BB];
                float ef = efs[il][f & 1];
                float sc = (s4[c][a] + bd + ef) * SCALE;
                if (f & 2) sc -= 1e30f;
                s4[c][a] = sc;
            }
        }
#pragma unroll
        for (int c = 0; c < 4; c++)
            *(float4*)&ps[ty * 4 + c][tx * 4] =
                make_float4(s4[c][0], s4[c][1], s4[c][2], s4[c][3]);
        __syncthreads();

        // online softmax: 4 threads per row
        {
            const int row = t >> 2, sl = t & 3;
            float vals[16];
#pragma unroll
            for (int g = 0; g < 4; g++)
                f4a(*(const float4*)&ps[row][sl * 16 + g * 4], &vals[g * 4]);
            float mloc = vals[0];
#pragma unroll
            for (int e = 1; e < 16; e++) mloc = fmaxf(mloc, vals[e]);
            mloc = fmaxf(mloc, __shfl_xor(mloc, 1));
            mloc = fmaxf(mloc, __shfl_xor(mloc, 2));
            const float mold = m_s[row];
            const float mnew = fmaxf(mold, mloc);
            const float corr = __expf(mold - mnew);
            float psum = 0.f;
#pragma unroll
            for (int e = 0; e < 16; e++) {
                float p = __expf(vals[e] - mnew);
                vals[e] = p;
                psum += p;
            }
#pragma unroll
            for (int g = 0; g < 4; g++)
                *(float4*)&ps[row][sl * 16 + g * 4] =
                    make_float4(vals[g * 4 + 0], vals[g * 4 + 1], vals[g * 4 + 2],
                                vals[g * 4 + 3]);
            psum += __shfl_xor(psum, 1);
            psum += __shfl_xor(psum, 2);
            if (sl == 0) {
                l_s[row] = l_s[row] * corr + psum;
                m_s[row] = mnew;
                corr_s[row] = corr;
            }
        }
        __syncthreads();

        // PV accumulate
#pragma unroll
        for (int c = 0; c < 4; c++) {
            const float corr = corr_s[ty * 4 + c];
#pragma unroll
            for (int a = 0; a < 4; a++) acc[c][a] *= corr;
        }
#pragma unroll 4
        for (int jj = 0; jj < 16; jj++) {
            float pr[4][4];
#pragma unroll
            for (int c = 0; c < 4; c++)
                f4a(*(const float4*)&ps[ty * 4 + c][jj * 4], pr[c]);
#pragma unroll
            for (int e = 0; e < 4; e++) {
                float vv[4];
                f4a(*(const float4*)&vs[jj * 4 + e][tx * 4], vv);
#pragma unroll
                for (int c = 0; c < 4; c++)
#pragma unroll
                    for (int a = 0; a < 4; a++) acc[c][a] += pr[c][e] * vv[a];
            }
        }
        __syncthreads();
    }

    // epilogue: normalize and write attn_vec as [row = i*BB+b][n*64+dv]
#pragma unroll
    for (int c = 0; c < 4; c++) {
        const int il = ty * 4 + c;
        const float linv = 1.f / l_s[il];
        const size_t row = (size_t)(i0 + il) * BB + b;
        *(float4*)&av[row * DD + n * DHH + tx * 4] = make_float4(
            acc[c][0] * linv, acc[c][1] * linv, acc[c][2] * linv, acc[c][3] * linv);
    }
}

// ---------------------------------------------------------------------------
// Output projection: out[row][h] = sum_k A[row][k] * Wo[h][k] + hres[row][h]
// grid: (2048/64, 1024/64)
// ---------------------------------------------------------------------------
__global__ __launch_bounds__(256) void k_oproj(const float* __restrict__ A,
                                               const float* __restrict__ Wo,
                                               const float* __restrict__ hres,
                                               float* __restrict__ outp) {
    __shared__ float As[32][68];
    __shared__ float Bs[32][68];
    const int r0 = blockIdx.x * 64, h0 = blockIdx.y * 64;
    const int t = threadIdx.x, tx = t & 15, ty = t >> 4;
    float acc[4][4] = {};
    for (int k0 = 0; k0 < DD; k0 += 32) {
#pragma unroll
        for (int e = 0; e < 2; e++) {
            int idx = t + 256 * e;
            int row = idx >> 3, kq = idx & 7;
            float4 v = *(const float4*)&A[(size_t)(r0 + row) * DD + k0 + kq * 4];
            As[kq * 4 + 0][row] = v.x;
            As[kq * 4 + 1][row] = v.y;
            As[kq * 4 + 2][row] = v.z;
            As[kq * 4 + 3][row] = v.w;
        }
#pragma unroll
        for (int e = 0; e < 2; e++) {
            int idx = t + 256 * e;
            int hh = idx >> 3, kq = idx & 7;
            float4 v = *(const float4*)&Wo[(size_t)(h0 + hh) * DD + k0 + kq * 4];
            Bs[kq * 4 + 0][hh] = v.x;
            Bs[kq * 4 + 1][hh] = v.y;
            Bs[kq * 4 + 2][hh] = v.z;
            Bs[kq * 4 + 3][hh] = v.w;
        }
        __syncthreads();
#pragma unroll 8
        for (int kk = 0; kk < 32; kk++) {
            float xa[4], wb[4];
            f4a(*(const float4*)&As[kk][ty * 4], xa);
            f4a(*(const float4*)&Bs[kk][tx * 4], wb);
#pragma unroll
            for (int c = 0; c < 4; c++)
#pragma unroll
                for (int a = 0; a < 4; a++) acc[c][a] += xa[c] * wb[a];
        }
        __syncthreads();
    }
#pragma unroll
    for (int c = 0; c < 4; c++) {
        const size_t row = r0 + ty * 4 + c;
        float4 hr = *(const float4*)&hres[row * DD + h0 + tx * 4];
        *(float4*)&outp[row * DD + h0 + tx * 4] =
            make_float4(acc[c][0] + hr.x, acc[c][1] + hr.y, acc[c][2] + hr.z,
                        acc[c][3] + hr.w);
    }
}

// ---------------------------------------------------------------------------
// LayerNorm over D per (i,b) row. One block per row.
// ---------------------------------------------------------------------------
__global__ __launch_bounds__(256) void k_ln(const float* __restrict__ ao,
                                            const float* __restrict__ gamma,
                                            const float* __restrict__ beta,
                                            float* __restrict__ outp) {
    const int row = blockIdx.x;
    const int t = threadIdx.x;
    float4 x = *(const float4*)&ao[(size_t)row * DD + t * 4];
    float s = x.x + x.y + x.z + x.w;
    float ss = x.x * x.x + x.y * x.y + x.z * x.z + x.w * x.w;
#pragma unroll
    for (int o = 1; o < 64; o <<= 1) {
        s += __shfl_xor(s, o);
        ss += __shfl_xor(ss, o);
    }
    __shared__ float sbuf[4], ssbuf[4];
    const int w = t >> 6;
    if ((t & 63) == 0) {
        sbuf[w] = s;
        ssbuf[w] = ss;
    }
    __syncthreads();
    s = sbuf[0] + sbuf[1] + sbuf[2] + sbuf[3];
    ss = ssbuf[0] + ssbuf[1] + ssbuf[2] + ssbuf[3];
    const float mu = s * (1.f / 1024.f);
    const float var = ss * (1.f / 1024.f) - mu * mu;
    const float rs = rsqrtf(var + 1e-12f);
    float4 g = *(const float4*)&gamma[t * 4];
    float4 bt = *(const float4*)&beta[t * 4];
    float4 o4;
    o4.x = (x.x - mu) * rs * g.x + bt.x;
    o4.y = (x.y - mu) * rs * g.y + bt.y;
    o4.z = (x.z - mu) * rs * g.z + bt.z;
    o4.w = (x.w - mu) * rs * g.w + bt.w;
    *(float4*)&outp[(size_t)row * DD + t * 4] = o4;
}

// ---------------------------------------------------------------------------
extern "C" void kernel_launch(void* const* d_in, const int* in_sizes, int n_in,
                              void* d_out, int out_size, void* d_ws, size_t ws_size,
                              hipStream_t stream) {
    (void)in_sizes; (void)n_in; (void)out_size; (void)ws_size;
    const float* h        = (const float*)d_in[0];
    const float* mems     = (const float*)d_in[1];
    const float* r        = (const float*)d_in[2];
    const float* seg_mat  = (const float*)d_in[3];
    const float* attn_mask= (const float*)d_in[4];
    const float* q_w      = (const float*)d_in[5];
    const float* k_w      = (const float*)d_in[6];
    const float* v_w      = (const float*)d_in[7];
    const float* o_w      = (const float*)d_in[8];
    const float* r_w      = (const float*)d_in[9];
    const float* r_w_bias = (const float*)d_in[10];
    const float* r_r_bias = (const float*)d_in[11];
    const float* r_s_bias = (const float*)d_in[12];
    const float* seg_embed= (const float*)d_in[13];
    const float* ln_gamma = (const float*)d_in[14];
    const float* ln_beta  = (const float*)d_in[15];
    float* outp = (float*)d_out;

    // workspace carve (all 16B aligned)
    char* w = (char*)d_ws;
    float* qh  = (float*)w; w += (size_t)BB * NH * QLEN * DHH * 4;  //  8 MB
    float* kh  = (float*)w; w += (size_t)BB * NH * KLEN * DHH * 4;  // 16 MB
    float* vh  = (float*)w; w += (size_t)BB * NH * KLEN * DHH * 4;  // 16 MB
    float* krh = (float*)w; w += (size_t)BB * NH * RLEN * DHH * 4;  // 24 MB
    float* av  = (float*)w; w += (size_t)QLEN * BB * DD * 4;        //  8 MB
    float* ao  = (float*)w; w += (size_t)QLEN * BB * DD * 4;        //  8 MB
    unsigned char* flags = (unsigned char*)w; w += (size_t)QLEN * KLEN * BB;  // 4 MB
    __half* bdr = (__half*)w;  // 512 * 64 * 2112 halves = 138.4 MB

    k_pack<<<(QLEN * KLEN * BB) / 256, 256, 0, stream>>>(seg_mat, attn_mask, flags);

    k_proj<<<dim3(QLEN / 64, NH, BB), 256, 0, stream>>>(h, h, QLEN, QLEN, q_w, qh);
    k_proj<<<dim3(KLEN / 64, NH, BB), 256, 0, stream>>>(mems, h, MLEN, KLEN, k_w, kh);
    k_proj<<<dim3(KLEN / 64, NH, BB), 256, 0, stream>>>(mems, h, MLEN, KLEN, v_w, vh);
    k_proj<<<dim3(RLEN / 64, NH, BB), 256, 0, stream>>>(r, r, RLEN, RLEN, r_w, krh);

    k_bdr<<<dim3(16, 32), 256, 0, stream>>>(qh, krh, r_r_bias, bdr);

    k_scorepv<<<dim3(16, 32), 256, 0, stream>>>(qh, kh, vh, bdr, flags, r_w_bias,
                                                r_s_bias, seg_embed, av);

    k_oproj<<<dim3((QLEN * BB) / 64, DD / 64), 256, 0, stream>>>(av, o_w, h, ao);

    k_ln<<<QLEN * BB, 256, 0, stream>>>(ao, ln_gamma, ln_beta, outp);
}

// Round 10
// 749.717 us; speedup vs baseline: 1.5399x; 1.5399x over previous
//
#include <hip/hip_runtime.h>
#include <hip/hip_fp16.h>

#define QLEN 1024
#define MLEN 1024
#define KLEN 2048
#define RLEN 3072
#define BB 2
#define NH 16
#define DHH 64
#define DD 1024
#define SCALE 0.125f
#define UW 2112  // padded bdr band width (needed 2111)

typedef float f32x4 __attribute__((ext_vector_type(4)));
typedef short bfx8 __attribute__((ext_vector_type(8)));

__device__ __forceinline__ void f4a(float4 v, float* a) {
    a[0] = v.x; a[1] = v.y; a[2] = v.z; a[3] = v.w;
}

// RNE f32 -> bf16 (bit pattern), no dependency on HIP bf16 type internals.
__device__ __forceinline__ unsigned short f2bf(float f) {
    unsigned int u = __float_as_uint(f);
    unsigned int lsb = (u >> 16) & 1u;
    u += 0x7fffu + lsb;
    return (unsigned short)(u >> 16);
}

// ---------------------------------------------------------------------------
// Pack seg_mat(one-hot diff bit) + attn_mask(0/1) into 1 byte per (i,j,b).
// ---------------------------------------------------------------------------
__global__ __launch_bounds__(256) void k_pack(const float* __restrict__ seg,
                                              const float* __restrict__ msk,
                                              unsigned char* __restrict__ flags) {
    const int idx = blockIdx.x * 256 + threadIdx.x;
    const float diff = seg[(size_t)idx * 2 + 1];
    const float mk = msk[idx];
    flags[idx] = (unsigned char)((diff > 0.5f ? 1 : 0) | (mk > 0.5f ? 2 : 0));
}

// ---------------------------------------------------------------------------
// Elementwise f32 -> bf16 for h, mems, r, o_w (8 elems/thread).
// ---------------------------------------------------------------------------
__global__ __launch_bounds__(256) void k_cvt_all(
    const float* __restrict__ h, const float* __restrict__ mems,
    const float* __restrict__ r, const float* __restrict__ ow,
    unsigned short* __restrict__ hb, unsigned short* __restrict__ mb,
    unsigned short* __restrict__ rb, unsigned short* __restrict__ owb) {
    const int blk = blockIdx.x;
    const float* src; unsigned short* dst; int base;
    if (blk < 1024)      { src = h;    dst = hb;  base = blk; }
    else if (blk < 2048) { src = mems; dst = mb;  base = blk - 1024; }
    else if (blk < 5120) { src = r;    dst = rb;  base = blk - 2048; }
    else                 { src = ow;   dst = owb; base = blk - 5120; }
    const size_t idx = ((size_t)base * 256 + threadIdx.x) * 8;
    float4 v0 = *(const float4*)&src[idx];
    float4 v1 = *(const float4*)&src[idx + 4];
    bfx8 o;
    o[0] = (short)f2bf(v0.x); o[1] = (short)f2bf(v0.y);
    o[2] = (short)f2bf(v0.z); o[3] = (short)f2bf(v0.w);
    o[4] = (short)f2bf(v1.x); o[5] = (short)f2bf(v1.y);
    o[6] = (short)f2bf(v1.z); o[7] = (short)f2bf(v1.w);
    *(bfx8*)&dst[idx] = o;
}

// ---------------------------------------------------------------------------
// Transpose + convert: W[k=1024][n=1024] f32 -> Wb[n][k] bf16. 64x64 tiles.
// z selects which of the 4 head-projection weights.
// ---------------------------------------------------------------------------
__global__ __launch_bounds__(256) void k_cvtT(
    const float* __restrict__ w0, const float* __restrict__ w1,
    const float* __restrict__ w2, const float* __restrict__ w3,
    unsigned short* __restrict__ o0, unsigned short* __restrict__ o1,
    unsigned short* __restrict__ o2, unsigned short* __restrict__ o3) {
    __shared__ float Ts[64][65];
    const float* W; unsigned short* Wb;
    switch (blockIdx.z) {
        case 0:  W = w0; Wb = o0; break;
        case 1:  W = w1; Wb = o1; break;
        case 2:  W = w2; Wb = o2; break;
        default: W = w3; Wb = o3; break;
    }
    const int k0 = blockIdx.x * 64, n0 = blockIdx.y * 64;
    const int t = threadIdx.x;
#pragma unroll
    for (int e = 0; e < 4; e++) {
        int row = e * 16 + (t >> 4), col = (t & 15) * 4;
        *(float4*)&Ts[row][col] = *(const float4*)&W[(size_t)(k0 + row) * 1024 + n0 + col];
    }
    __syncthreads();
    const int n_l = t >> 2, kc = (t & 3) * 16;
    bfx8 a, b;
#pragma unroll
    for (int i = 0; i < 8; i++) a[i] = (short)f2bf(Ts[kc + i][n_l]);
#pragma unroll
    for (int i = 0; i < 8; i++) b[i] = (short)f2bf(Ts[kc + 8 + i][n_l]);
    unsigned short* dst = &Wb[(size_t)(n0 + n_l) * 1024 + k0 + kc];
    *(bfx8*)dst = a;
    *(bfx8*)(dst + 8) = b;
}

// ---------------------------------------------------------------------------
// bf16 MFMA GEMM, 128x128 tile, BK=32, 4 waves, 4x4 16x16x32 frags/wave.
// A: [M][1024] bf16, rows: row<split -> A0 else A1, row stride `rowstride`,
//    plus b*bstride column offset (b = blockIdx.z).
// B: Bm[n][k] bf16 (k contiguous).
// MODE 0: out[((b*16+head)*R + row)*64 + dh] = acc      (head = col>>6)
// MODE 1: out[row*1024 + col] = acc + res[row*1024+col]
// A/B frags use the SAME (lane-group,elem)->k fill, so the result is correct
// for any internal HW k-permutation (dot-product slot pairing invariance).
// ---------------------------------------------------------------------------
template <int MODE>
__global__ __launch_bounds__(256) void k_gemm(
    const unsigned short* __restrict__ A0, const unsigned short* __restrict__ A1,
    const int split, const int rowstride, const int bstride,
    const unsigned short* __restrict__ Bm, const float* __restrict__ res,
    float* __restrict__ outp, const int R) {
    __shared__ __align__(16) unsigned short As[128 * 32];
    __shared__ __align__(16) unsigned short Bs[128 * 32];
    const int t = threadIdx.x;
    const int wave = t >> 6, lane = t & 63;
    const int r0 = blockIdx.x * 128, c0 = blockIdx.y * 128;
    const int b = blockIdx.z;
    const int wr = (wave >> 1) * 64, wc = (wave & 1) * 64;
    const int bofs = b * bstride;

    f32x4 acc[4][4];
#pragma unroll
    for (int m = 0; m < 4; m++)
#pragma unroll
        for (int n = 0; n < 4; n++) acc[m][n] = (f32x4)0.f;

    const int srow = t >> 2;          // staging row 0..63 (+64 on 2nd subiter)
    const int skc = (t & 3) * 8;      // staging k offset
    const unsigned short* arow[2];
    const unsigned short* brow[2];
#pragma unroll
    for (int e = 0; e < 2; e++) {
        int rg = r0 + srow + e * 64;
        arow[e] = ((rg < split) ? (A0 + (size_t)rg * rowstride)
                                : (A1 + (size_t)(rg - split) * rowstride)) + bofs;
        brow[e] = Bm + (size_t)(c0 + srow + e * 64) * 1024;
    }

    const int l15 = lane & 15, kc8 = (lane >> 4) * 8;
    for (int k0 = 0; k0 < 1024; k0 += 32) {
#pragma unroll
        for (int e = 0; e < 2; e++) {
            *(bfx8*)&As[(srow + e * 64) * 32 + skc] = *(const bfx8*)(arow[e] + k0 + skc);
            *(bfx8*)&Bs[(srow + e * 64) * 32 + skc] = *(const bfx8*)(brow[e] + k0 + skc);
        }
        __syncthreads();
        bfx8 af[4], bfr[4];
#pragma unroll
        for (int m = 0; m < 4; m++)
            af[m] = *(const bfx8*)&As[(wr + m * 16 + l15) * 32 + kc8];
#pragma unroll
        for (int n = 0; n < 4; n++)
            bfr[n] = *(const bfx8*)&Bs[(wc + n * 16 + l15) * 32 + kc8];
#pragma unroll
        for (int m = 0; m < 4; m++)
#pragma unroll
            for (int n = 0; n < 4; n++)
                acc[m][n] = __builtin_amdgcn_mfma_f32_16x16x32_bf16(
                    af[m], bfr[n], acc[m][n], 0, 0, 0);
        __syncthreads();
    }

    const int rq = (lane >> 4) * 4;
#pragma unroll
    for (int m = 0; m < 4; m++) {
#pragma unroll
        for (int n = 0; n < 4; n++) {
            const int colg = c0 + wc + n * 16 + l15;
            if (MODE == 0) {
                const int head = colg >> 6, dh = colg & 63;
                const size_t ob = ((size_t)(b * 16 + head) * R) * 64 + dh;
#pragma unroll
                for (int q = 0; q < 4; q++) {
                    const int rowg = r0 + wr + m * 16 + rq + q;
                    outp[ob + (size_t)rowg * 64] = acc[m][n][q];
                }
            } else {
#pragma unroll
                for (int q = 0; q < 4; q++) {
                    const int rowg = r0 + wr + m * 16 + rq + q;
                    const size_t o = (size_t)rowg * 1024 + colg;
                    outp[o] = acc[m][n][q] + res[o];
                }
            }
        }
    }
}

// ---------------------------------------------------------------------------
// Banded position-term GEMM (f32, unchanged).
// ---------------------------------------------------------------------------
__global__ __launch_bounds__(256) void k_bdr(const float* __restrict__ qh,
                                             const float* __restrict__ krh,
                                             const float* __restrict__ rr_bias,
                                             __half* __restrict__ bdr) {
    __shared__ float qr_t[64][68];  // [d][i]
    __shared__ float kr_t[64][68];  // [d][u]
    const int itile = blockIdx.x, bn = blockIdx.y;
    const int n = bn & 15;
    const int i0 = itile * 64;
    const int t = threadIdx.x, tx = t & 15, ty = t >> 4;
#pragma unroll
    for (int e = 0; e < 4; e++) {
        int idx = t + 256 * e;
        int i = idx >> 4, dq = idx & 15;
        float4 qv = *(const float4*)&qh[((size_t)bn * QLEN + i0 + i) * DHH + dq * 4];
        float4 br = *(const float4*)&rr_bias[n * DHH + dq * 4];
        qr_t[dq * 4 + 0][i] = qv.x + br.x;
        qr_t[dq * 4 + 1][i] = qv.y + br.y;
        qr_t[dq * 4 + 2][i] = qv.z + br.z;
        qr_t[dq * 4 + 3][i] = qv.w + br.w;
    }
    const int jrbase = QLEN - i0 - 63;
    const size_t obase = ((size_t)bn * 16 + itile) * 64 * UW;
    __syncthreads();
    for (int ut = 0; ut < 33; ut++) {
        const int u0 = ut * 64;
#pragma unroll
        for (int e = 0; e < 4; e++) {
            int idx = t + 256 * e;
            int u = idx >> 4, dq = idx & 15;
            int jr = jrbase + u0 + u;
            if (jr > RLEN - 1) jr = RLEN - 1;
            float4 kv = *(const float4*)&krh[((size_t)bn * RLEN + jr) * DHH + dq * 4];
            kr_t[dq * 4 + 0][u] = kv.x;
            kr_t[dq * 4 + 1][u] = kv.y;
            kr_t[dq * 4 + 2][u] = kv.z;
            kr_t[dq * 4 + 3][u] = kv.w;
        }
        __syncthreads();
        float acc[4][4] = {};
#pragma unroll 8
        for (int d = 0; d < 64; d++) {
            float qa[4], kb[4];
            f4a(*(const float4*)&qr_t[d][ty * 4], qa);
            f4a(*(const float4*)&kr_t[d][tx * 4], kb);
#pragma unroll
            for (int c = 0; c < 4; c++)
#pragma unroll
                for (int a = 0; a < 4; a++) acc[c][a] += qa[c] * kb[a];
        }
#pragma unroll
        for (int c = 0; c < 4; c++) {
            __half2* wp = (__half2*)&bdr[obase + (size_t)(ty * 4 + c) * UW + u0 + tx * 4];
            wp[0] = __floats2half2_rn(acc[c][0], acc[c][1]);
            wp[1] = __floats2half2_rn(acc[c][2], acc[c][3]);
        }
        __syncthreads();
    }
}

// ---------------------------------------------------------------------------
// Fused scores + online softmax + PV (f32, unchanged except bf16 av output).
// ---------------------------------------------------------------------------
__global__ __launch_bounds__(256) void k_scorepv(
    const float* __restrict__ qh, const float* __restrict__ kh,
    const float* __restrict__ vh, const __half* __restrict__ bdr,
    const unsigned char* __restrict__ flags, const float* __restrict__ rw_bias,
    const float* __restrict__ rs_bias, const float* __restrict__ seg_embed,
    unsigned short* __restrict__ avb) {
    __shared__ float qc_t[64][68];
    __shared__ float ks_t[64][68];
    __shared__ float vs[64][68];
    __shared__ float ps[64][68];
    __shared__ float efs[64][2];
    __shared__ float m_s[64], l_s[64], corr_s[64];

    const int itile = blockIdx.x, bn = blockIdx.y;
    const int b = bn >> 4, n = bn & 15;
    const int i0 = itile * 64;
    const int t = threadIdx.x, tx = t & 15, ty = t >> 4;

#pragma unroll
    for (int e = 0; e < 4; e++) {
        int idx = t + 256 * e;
        int i = idx >> 4, dq = idx & 15;
        float4 qv = *(const float4*)&qh[((size_t)bn * QLEN + i0 + i) * DHH + dq * 4];
        float4 bw = *(const float4*)&rw_bias[n * DHH + dq * 4];
        qc_t[dq * 4 + 0][i] = qv.x + bw.x;
        qc_t[dq * 4 + 1][i] = qv.y + bw.y;
        qc_t[dq * 4 + 2][i] = qv.z + bw.z;
        qc_t[dq * 4 + 3][i] = qv.w + bw.w;
    }
    if (t < 64) {
        m_s[t] = -3.0e38f;
        l_s[t] = 0.f;
    }
    __syncthreads();
    if (t < 128) {
        int i = t >> 1, s = t & 1;
        float sum = 0.f;
        for (int d = 0; d < DHH; d++) {
            float qraw = qc_t[d][i] - rw_bias[n * DHH + d] + rs_bias[n * DHH + d];
            sum += qraw * seg_embed[(s * NH + n) * DHH + d];
        }
        efs[i][s] = sum;
    }
    __syncthreads();

    float acc[4][4] = {};
    const size_t bdbase = ((size_t)bn * 16 + itile) * 64 * UW;

    for (int jt = 0; jt < 32; jt++) {
        const int j0 = jt * 64;
#pragma unroll
        for (int e = 0; e < 4; e++) {
            int idx = t + 256 * e;
            int j = idx >> 4, dq = idx & 15;
            size_t g = ((size_t)bn * KLEN + j0 + j) * DHH + dq * 4;
            float4 kv = *(const float4*)&kh[g];
            ks_t[dq * 4 + 0][j] = kv.x;
            ks_t[dq * 4 + 1][j] = kv.y;
            ks_t[dq * 4 + 2][j] = kv.z;
            ks_t[dq * 4 + 3][j] = kv.w;
            *(float4*)&vs[j][dq * 4] = *(const float4*)&vh[g];
        }
        __syncthreads();

        float s4[4][4] = {};
#pragma unroll 8
        for (int d = 0; d < 64; d++) {
            float qa[4], kb[4];
            f4a(*(const float4*)&qc_t[d][ty * 4], qa);
            f4a(*(const float4*)&ks_t[d][tx * 4], kb);
#pragma unroll
            for (int c = 0; c < 4; c++)
#pragma unroll
                for (int a = 0; a < 4; a++) s4[c][a] += qa[c] * kb[a];
        }
#pragma unroll
        for (int c = 0; c < 4; c++) {
            const int il = ty * 4 + c;
            const int gi = i0 + il;
            const __half* bp = &bdr[bdbase + (size_t)il * UW + (j0 + tx * 4 + 63 - il)];
            const unsigned char* fp = &flags[((size_t)gi * KLEN + j0 + tx * 4) * BB + b];
#pragma unroll
            for (int a = 0; a < 4; a++) {
                float bd = __half2float(bp[a]);
                unsigned char f = fp[a * BB];
                float ef = efs[il][f & 1];
                float sc = (s4[c][a] + bd + ef) * SCALE;
                if (f & 2) sc -= 1e30f;
                s4[c][a] = sc;
            }
        }
#pragma unroll
        for (int c = 0; c < 4; c++)
            *(float4*)&ps[ty * 4 + c][tx * 4] =
                make_float4(s4[c][0], s4[c][1], s4[c][2], s4[c][3]);
        __syncthreads();

        {
            const int row = t >> 2, sl = t & 3;
            float vals[16];
#pragma unroll
            for (int g = 0; g < 4; g++)
                f4a(*(const float4*)&ps[row][sl * 16 + g * 4], &vals[g * 4]);
            float mloc = vals[0];
#pragma unroll
            for (int e = 1; e < 16; e++) mloc = fmaxf(mloc, vals[e]);
            mloc = fmaxf(mloc, __shfl_xor(mloc, 1));
            mloc = fmaxf(mloc, __shfl_xor(mloc, 2));
            const float mold = m_s[row];
            const float mnew = fmaxf(mold, mloc);
            const float corr = __expf(mold - mnew);
            float psum = 0.f;
#pragma unroll
            for (int e = 0; e < 16; e++) {
                float p = __expf(vals[e] - mnew);
                vals[e] = p;
                psum += p;
            }
#pragma unroll
            for (int g = 0; g < 4; g++)
                *(float4*)&ps[row][sl * 16 + g * 4] =
                    make_float4(vals[g * 4 + 0], vals[g * 4 + 1], vals[g * 4 + 2],
                                vals[g * 4 + 3]);
            psum += __shfl_xor(psum, 1);
            psum += __shfl_xor(psum, 2);
            if (sl == 0) {
                l_s[row] = l_s[row] * corr + psum;
                m_s[row] = mnew;
                corr_s[row] = corr;
            }
        }
        __syncthreads();

#pragma unroll
        for (int c = 0; c < 4; c++) {
            const float corr = corr_s[ty * 4 + c];
#pragma unroll
            for (int a = 0; a < 4; a++) acc[c][a] *= corr;
        }
#pragma unroll 4
        for (int jj = 0; jj < 16; jj++) {
            float pr[4][4];
#pragma unroll
            for (int c = 0; c < 4; c++)
                f4a(*(const float4*)&ps[ty * 4 + c][jj * 4], pr[c]);
#pragma unroll
            for (int e = 0; e < 4; e++) {
                float vv[4];
                f4a(*(const float4*)&vs[jj * 4 + e][tx * 4], vv);
#pragma unroll
                for (int c = 0; c < 4; c++)
#pragma unroll
                    for (int a = 0; a < 4; a++) acc[c][a] += pr[c][e] * vv[a];
            }
        }
        __syncthreads();
    }

    // epilogue: normalize, convert to bf16, write [row = i*BB+b][n*64+dv]
#pragma unroll
    for (int c = 0; c < 4; c++) {
        const int il = ty * 4 + c;
        const float linv = 1.f / l_s[il];
        const size_t row = (size_t)(i0 + il) * BB + b;
        short4 o;
        o.x = (short)f2bf(acc[c][0] * linv);
        o.y = (short)f2bf(acc[c][1] * linv);
        o.z = (short)f2bf(acc[c][2] * linv);
        o.w = (short)f2bf(acc[c][3] * linv);
        *(short4*)&avb[row * DD + n * DHH + tx * 4] = o;
    }
}

// ---------------------------------------------------------------------------
// LayerNorm over D per (i,b) row (unchanged).
// ---------------------------------------------------------------------------
__global__ __launch_bounds__(256) void k_ln(const float* __restrict__ ao,
                                            const float* __restrict__ gamma,
                                            const float* __restrict__ beta,
                                            float* __restrict__ outp) {
    const int row = blockIdx.x;
    const int t = threadIdx.x;
    float4 x = *(const float4*)&ao[(size_t)row * DD + t * 4];
    float s = x.x + x.y + x.z + x.w;
    float ss = x.x * x.x + x.y * x.y + x.z * x.z + x.w * x.w;
#pragma unroll
    for (int o = 1; o < 64; o <<= 1) {
        s += __shfl_xor(s, o);
        ss += __shfl_xor(ss, o);
    }
    __shared__ float sbuf[4], ssbuf[4];
    const int w = t >> 6;
    if ((t & 63) == 0) {
        sbuf[w] = s;
        ssbuf[w] = ss;
    }
    __syncthreads();
    s = sbuf[0] + sbuf[1] + sbuf[2] + sbuf[3];
    ss = ssbuf[0] + ssbuf[1] + ssbuf[2] + ssbuf[3];
    const float mu = s * (1.f / 1024.f);
    const float var = ss * (1.f / 1024.f) - mu * mu;
    const float rs = rsqrtf(var + 1e-12f);
    float4 g = *(const float4*)&gamma[t * 4];
    float4 bt = *(const float4*)&beta[t * 4];
    float4 o4;
    o4.x = (x.x - mu) * rs * g.x + bt.x;
    o4.y = (x.y - mu) * rs * g.y + bt.y;
    o4.z = (x.z - mu) * rs * g.z + bt.z;
    o4.w = (x.w - mu) * rs * g.w + bt.w;
    *(float4*)&outp[(size_t)row * DD + t * 4] = o4;
}

// ---------------------------------------------------------------------------
extern "C" void kernel_launch(void* const* d_in, const int* in_sizes, int n_in,
                              void* d_out, int out_size, void* d_ws, size_t ws_size,
                              hipStream_t stream) {
    (void)in_sizes; (void)n_in; (void)out_size; (void)ws_size;
    const float* h        = (const float*)d_in[0];
    const float* mems     = (const float*)d_in[1];
    const float* r        = (const float*)d_in[2];
    const float* seg_mat  = (const float*)d_in[3];
    const float* attn_mask= (const float*)d_in[4];
    const float* q_w      = (const float*)d_in[5];
    const float* k_w      = (const float*)d_in[6];
    const float* v_w      = (const float*)d_in[7];
    const float* o_w      = (const float*)d_in[8];
    const float* r_w      = (const float*)d_in[9];
    const float* r_w_bias = (const float*)d_in[10];
    const float* r_r_bias = (const float*)d_in[11];
    const float* r_s_bias = (const float*)d_in[12];
    const float* seg_embed= (const float*)d_in[13];
    const float* ln_gamma = (const float*)d_in[14];
    const float* ln_beta  = (const float*)d_in[15];
    float* outp = (float*)d_out;

    // workspace carve (all 16B aligned); total ~240 MB
    char* w = (char*)d_ws;
    unsigned short* hb  = (unsigned short*)w; w += (size_t)2097152 * 2;  // 4 MB
    unsigned short* mb  = (unsigned short*)w; w += (size_t)2097152 * 2;  // 4 MB
    unsigned short* rb  = (unsigned short*)w; w += (size_t)6291456 * 2;  // 12 MB
    unsigned short* owb = (unsigned short*)w; w += (size_t)1048576 * 2;  // 2 MB
    unsigned short* qwb = (unsigned short*)w; w += (size_t)1048576 * 2;
    unsigned short* kwb = (unsigned short*)w; w += (size_t)1048576 * 2;
    unsigned short* vwb = (unsigned short*)w; w += (size_t)1048576 * 2;
    unsigned short* rwb = (unsigned short*)w; w += (size_t)1048576 * 2;
    float* qh  = (float*)w; w += (size_t)BB * NH * QLEN * DHH * 4;  //  8 MB
    float* kh  = (float*)w; w += (size_t)BB * NH * KLEN * DHH * 4;  // 16 MB
    float* vh  = (float*)w; w += (size_t)BB * NH * KLEN * DHH * 4;  // 16 MB
    float* krh = (float*)w; w += (size_t)BB * NH * RLEN * DHH * 4;  // 24 MB
    unsigned short* avb = (unsigned short*)w; w += (size_t)2097152 * 2;  // 4 MB
    unsigned char* flags = (unsigned char*)w; w += (size_t)QLEN * KLEN * BB;  // 4 MB
    __half* bdr = (__half*)w;  // 138.4 MB
    float* ao = qh;  // reuse: qh dead after k_scorepv, oproj writes here

    k_pack<<<(QLEN * KLEN * BB) / 256, 256, 0, stream>>>(seg_mat, attn_mask, flags);
    k_cvt_all<<<5632, 256, 0, stream>>>(h, mems, r, o_w, hb, mb, rb, owb);
    k_cvtT<<<dim3(16, 16, 4), 256, 0, stream>>>(q_w, k_w, v_w, r_w, qwb, kwb, vwb, rwb);

    k_gemm<0><<<dim3(8, 8, 2), 256, 0, stream>>>(hb, hb, 1024, 2048, 1024, qwb,
                                                 nullptr, qh, QLEN);
    k_gemm<0><<<dim3(16, 8, 2), 256, 0, stream>>>(mb, hb, 1024, 2048, 1024, kwb,
                                                  nullptr, kh, KLEN);
    k_gemm<0><<<dim3(16, 8, 2), 256, 0, stream>>>(mb, hb, 1024, 2048, 1024, vwb,
                                                  nullptr, vh, KLEN);
    k_gemm<0><<<dim3(24, 8, 2), 256, 0, stream>>>(rb, rb, 3072, 2048, 1024, rwb,
                                                  nullptr, krh, RLEN);

    k_bdr<<<dim3(16, 32), 256, 0, stream>>>(qh, krh, r_r_bias, bdr);

    k_scorepv<<<dim3(16, 32), 256, 0, stream>>>(qh, kh, vh, bdr, flags, r_w_bias,
                                                r_s_bias, seg_embed, avb);

    k_gemm<1><<<dim3(16, 8, 1), 256, 0, stream>>>(avb, avb, 2048, 1024, 0, owb,
                                                  h, ao, 0);

    k_ln<<<QLEN * BB, 256, 0, stream>>>(ao, ln_gamma, ln_beta, outp);
}

// Round 11
// 413.972 us; speedup vs baseline: 2.7887x; 1.8110x over previous
//
#include <hip/hip_runtime.h>
#include <hip/hip_fp16.h>

#define QLEN 1024
#define MLEN 1024
#define KLEN 2048
#define RLEN 3072
#define BB 2
#define NH 16
#define DHH 64
#define DD 1024
#define SCALE 0.125f

typedef float f32x4 __attribute__((ext_vector_type(4)));
typedef short bfx8 __attribute__((ext_vector_type(8)));

// RNE f32 -> bf16 (bit pattern).
__device__ __forceinline__ unsigned short f2bf(float f) {
    unsigned int u = __float_as_uint(f);
    unsigned int lsb = (u >> 16) & 1u;
    u += 0x7fffu + lsb;
    return (unsigned short)(u >> 16);
}

// ---------------------------------------------------------------------------
// Pack seg_mat(one-hot diff bit) + attn_mask(0/1) into 1 byte per (i,j,b).
// ---------------------------------------------------------------------------
__global__ __launch_bounds__(256) void k_pack(const float* __restrict__ seg,
                                              const float* __restrict__ msk,
                                              unsigned char* __restrict__ flags) {
    const int idx = blockIdx.x * 256 + threadIdx.x;
    const float diff = seg[(size_t)idx * 2 + 1];
    const float mk = msk[idx];
    flags[idx] = (unsigned char)((diff > 0.5f ? 1 : 0) | (mk > 0.5f ? 2 : 0));
}

// ---------------------------------------------------------------------------
// Elementwise f32 -> bf16 for h, mems, r, o_w (8 elems/thread).
// ---------------------------------------------------------------------------
__global__ __launch_bounds__(256) void k_cvt_all(
    const float* __restrict__ h, const float* __restrict__ mems,
    const float* __restrict__ r, const float* __restrict__ ow,
    unsigned short* __restrict__ hb, unsigned short* __restrict__ mb,
    unsigned short* __restrict__ rb, unsigned short* __restrict__ owb) {
    const int blk = blockIdx.x;
    const float* src; unsigned short* dst; int base;
    if (blk < 1024)      { src = h;    dst = hb;  base = blk; }
    else if (blk < 2048) { src = mems; dst = mb;  base = blk - 1024; }
    else if (blk < 5120) { src = r;    dst = rb;  base = blk - 2048; }
    else                 { src = ow;   dst = owb; base = blk - 5120; }
    const size_t idx = ((size_t)base * 256 + threadIdx.x) * 8;
    float4 v0 = *(const float4*)&src[idx];
    float4 v1 = *(const float4*)&src[idx + 4];
    bfx8 o;
    o[0] = (short)f2bf(v0.x); o[1] = (short)f2bf(v0.y);
    o[2] = (short)f2bf(v0.z); o[3] = (short)f2bf(v0.w);
    o[4] = (short)f2bf(v1.x); o[5] = (short)f2bf(v1.y);
    o[6] = (short)f2bf(v1.z); o[7] = (short)f2bf(v1.w);
    *(bfx8*)&dst[idx] = o;
}

// ---------------------------------------------------------------------------
// Transpose + convert: W[k=1024][n=1024] f32 -> Wb[n][k] bf16. 64x64 tiles.
// ---------------------------------------------------------------------------
__global__ __launch_bounds__(256) void k_cvtT(
    const float* __restrict__ w0, const float* __restrict__ w1,
    const float* __restrict__ w2, const float* __restrict__ w3,
    unsigned short* __restrict__ o0, unsigned short* __restrict__ o1,
    unsigned short* __restrict__ o2, unsigned short* __restrict__ o3) {
    __shared__ float Ts[64][65];
    const float* W; unsigned short* Wb;
    switch (blockIdx.z) {
        case 0:  W = w0; Wb = o0; break;
        case 1:  W = w1; Wb = o1; break;
        case 2:  W = w2; Wb = o2; break;
        default: W = w3; Wb = o3; break;
    }
    const int k0 = blockIdx.x * 64, n0 = blockIdx.y * 64;
    const int t = threadIdx.x;
#pragma unroll
    for (int e = 0; e < 4; e++) {
        int row = e * 16 + (t >> 4), col = (t & 15) * 4;
        *(float4*)&Ts[row][col] = *(const float4*)&W[(size_t)(k0 + row) * 1024 + n0 + col];
    }
    __syncthreads();
    const int n_l = t >> 2, kc = (t & 3) * 16;
    bfx8 a, b;
#pragma unroll
    for (int i = 0; i < 8; i++) a[i] = (short)f2bf(Ts[kc + i][n_l]);
#pragma unroll
    for (int i = 0; i < 8; i++) b[i] = (short)f2bf(Ts[kc + 8 + i][n_l]);
    unsigned short* dst = &Wb[(size_t)(n0 + n_l) * 1024 + k0 + kc];
    *(bfx8*)dst = a;
    *(bfx8*)(dst + 8) = b;
}

// ---------------------------------------------------------------------------
// bf16 MFMA GEMM, 128x128 tile, BK=32, 4 waves, 4x4 16x16x32 frags/wave.
// MODE 0: f32 head-layout out.  MODE 2: bf16 head-layout out.
// MODE 1: f32 out[row*1024+col] = acc + res.
// ---------------------------------------------------------------------------
template <int MODE>
__global__ __launch_bounds__(256) void k_gemm(
    const unsigned short* __restrict__ A0, const unsigned short* __restrict__ A1,
    const int split, const int rowstride, const int bstride,
    const unsigned short* __restrict__ Bm, const float* __restrict__ res,
    float* __restrict__ outp, const int R) {
    __shared__ __align__(16) unsigned short As[128 * 32];
    __shared__ __align__(16) unsigned short Bs[128 * 32];
    const int t = threadIdx.x;
    const int wave = t >> 6, lane = t & 63;
    const int r0 = blockIdx.x * 128, c0 = blockIdx.y * 128;
    const int b = blockIdx.z;
    const int wr = (wave >> 1) * 64, wc = (wave & 1) * 64;
    const int bofs = b * bstride;

    f32x4 acc[4][4];
#pragma unroll
    for (int m = 0; m < 4; m++)
#pragma unroll
        for (int n = 0; n < 4; n++) acc[m][n] = (f32x4)0.f;

    const int srow = t >> 2;
    const int skc = (t & 3) * 8;
    const unsigned short* arow[2];
    const unsigned short* brow[2];
#pragma unroll
    for (int e = 0; e < 2; e++) {
        int rg = r0 + srow + e * 64;
        arow[e] = ((rg < split) ? (A0 + (size_t)rg * rowstride)
                                : (A1 + (size_t)(rg - split) * rowstride)) + bofs;
        brow[e] = Bm + (size_t)(c0 + srow + e * 64) * 1024;
    }

    const int l15 = lane & 15, kc8 = (lane >> 4) * 8;
    for (int k0 = 0; k0 < 1024; k0 += 32) {
#pragma unroll
        for (int e = 0; e < 2; e++) {
            *(bfx8*)&As[(srow + e * 64) * 32 + skc] = *(const bfx8*)(arow[e] + k0 + skc);
            *(bfx8*)&Bs[(srow + e * 64) * 32 + skc] = *(const bfx8*)(brow[e] + k0 + skc);
        }
        __syncthreads();
        bfx8 af[4], bfr[4];
#pragma unroll
        for (int m = 0; m < 4; m++)
            af[m] = *(const bfx8*)&As[(wr + m * 16 + l15) * 32 + kc8];
#pragma unroll
        for (int n = 0; n < 4; n++)
            bfr[n] = *(const bfx8*)&Bs[(wc + n * 16 + l15) * 32 + kc8];
#pragma unroll
        for (int m = 0; m < 4; m++)
#pragma unroll
            for (int n = 0; n < 4; n++)
                acc[m][n] = __builtin_amdgcn_mfma_f32_16x16x32_bf16(
                    af[m], bfr[n], acc[m][n], 0, 0, 0);
        __syncthreads();
    }

    const int rq = (lane >> 4) * 4;
#pragma unroll
    for (int m = 0; m < 4; m++) {
#pragma unroll
        for (int n = 0; n < 4; n++) {
            const int colg = c0 + wc + n * 16 + l15;
            if (MODE == 0 || MODE == 2) {
                const int head = colg >> 6, dh = colg & 63;
                const size_t ob = ((size_t)(b * 16 + head) * R) * 64 + dh;
#pragma unroll
                for (int q = 0; q < 4; q++) {
                    const int rowg = r0 + wr + m * 16 + rq + q;
                    if (MODE == 0)
                        outp[ob + (size_t)rowg * 64] = acc[m][n][q];
                    else
                        ((unsigned short*)outp)[ob + (size_t)rowg * 64] = f2bf(acc[m][n][q]);
                }
            } else {
#pragma unroll
                for (int q = 0; q < 4; q++) {
                    const int rowg = r0 + wr + m * 16 + rq + q;
                    const size_t o = (size_t)rowg * 1024 + colg;
                    outp[o] = acc[m][n][q] + res[o];
                }
            }
        }
    }
}

// ---------------------------------------------------------------------------
// Fused MFMA scores (ac + banded bd + ef) + in-register online softmax + PV.
// One block = 64 q-rows x (b*n). 4 waves, each owns 16 rows.
// bd[il][jl] = qr[il] . kr[jrlo + v], v = jl + 63 - il; kr window 128 rows,
// double-buffered, slides 64/tile. Wave w covers v in [48-16w, 127-16w] with
// 5 aligned 16-wide MFMA band frags; diagonal gather via __shfl:
//   wrap = l15 > row; src = (lane&48)|((15-row+l15)&15); frag = nf + wrap.
// ---------------------------------------------------------------------------
__global__ __launch_bounds__(256) void k_scorepv_mfma(
    const float* __restrict__ qh, const unsigned short* __restrict__ khb,
    const unsigned short* __restrict__ vhb, const unsigned short* __restrict__ krhb,
    const unsigned char* __restrict__ flags, const float* __restrict__ rw_bias,
    const float* __restrict__ rr_bias, const float* __restrict__ rs_bias,
    const float* __restrict__ seg_embed, unsigned short* __restrict__ avb) {
    __shared__ __align__(16) unsigned short qcs[64][72];
    __shared__ __align__(16) unsigned short qrs[64][72];
    __shared__ __align__(16) unsigned short ks[64][72];
    __shared__ __align__(16) unsigned short vts[64][72];   // V transposed [dv][jl]
    __shared__ __align__(16) unsigned short krs[2][64][72];
    __shared__ __align__(16) unsigned short pws[4][16][72]; // per-wave P
    __shared__ float efs[64][2];

    const int itile = blockIdx.x, bn = blockIdx.y;
    const int b = bn >> 4, n = bn & 15;
    const int i0 = itile * 64;
    const int t = threadIdx.x;
    const int lane = t & 63, wave = t >> 6;
    const int l15 = lane & 15, kc8 = (lane >> 4) * 8;
    const int srow = t >> 2, sdb = (t & 3) * 16;

    // stage qc = q + rw_bias, qr = q + rr_bias (bf16)
    {
        const float* qp = &qh[((size_t)bn * QLEN + i0 + srow) * DHH + sdb];
#pragma unroll
        for (int e = 0; e < 4; e++) {
            float4 qv = *(const float4*)&qp[e * 4];
            float4 bw = *(const float4*)&rw_bias[n * DHH + sdb + e * 4];
            float4 br = *(const float4*)&rr_bias[n * DHH + sdb + e * 4];
            short4 c, r;
            c.x = (short)f2bf(qv.x + bw.x); c.y = (short)f2bf(qv.y + bw.y);
            c.z = (short)f2bf(qv.z + bw.z); c.w = (short)f2bf(qv.w + bw.w);
            r.x = (short)f2bf(qv.x + br.x); r.y = (short)f2bf(qv.y + br.y);
            r.z = (short)f2bf(qv.z + br.z); r.w = (short)f2bf(qv.w + br.w);
            *(short4*)&qcs[srow][sdb + e * 4] = c;
            *(short4*)&qrs[srow][sdb + e * 4] = r;
        }
    }
    if (t < 128) {  // efs[i][s] = (q_raw + rs_bias) . seg_embed[s][n][:]
        int i = t >> 1, s = t & 1;
        float sum = 0.f;
        for (int d = 0; d < DHH; d++) {
            float qraw = qh[((size_t)bn * QLEN + i0 + i) * DHH + d] + rs_bias[n * DHH + d];
            sum += qraw * seg_embed[(s * NH + n) * DHH + d];
        }
        efs[i][s] = sum;
    }
    __syncthreads();

    bfx8 qcf[2], qrf[2];
#pragma unroll
    for (int kk = 0; kk < 2; kk++) {
        qcf[kk] = *(const bfx8*)&qcs[wave * 16 + l15][kk * 32 + kc8];
        qrf[kk] = *(const bfx8*)&qrs[wave * 16 + l15][kk * 32 + kc8];
    }

    f32x4 acc[4];
#pragma unroll
    for (int nf = 0; nf < 4; nf++) acc[nf] = (f32x4)0.f;
    float m_r[4], l_r[4];
#pragma unroll
    for (int q = 0; q < 4; q++) { m_r[q] = -3.0e38f; l_r[q] = 0.f; }

    const int v0w = 48 - wave * 16;
    const int rowl = (lane >> 4) * 4;

    for (int jt = 0; jt < 32; jt++) {
        const int j0 = jt * 64;
        const int jrlo = QLEN + j0 - i0 - 63;  // >= 1
        __syncthreads();
        // stage K tile
        {
            const unsigned short* kp = &khb[((size_t)bn * KLEN + j0 + srow) * DHH + sdb];
            *(bfx8*)&ks[srow][sdb] = *(const bfx8*)kp;
            *(bfx8*)&ks[srow][sdb + 8] = *(const bfx8*)(kp + 8);
        }
        // stage V transposed
        {
            const unsigned short* vp = &vhb[((size_t)bn * KLEN + j0 + srow) * DHH + sdb];
            bfx8 v0 = *(const bfx8*)vp;
            bfx8 v1 = *(const bfx8*)(vp + 8);
#pragma unroll
            for (int e = 0; e < 8; e++) vts[sdb + e][srow] = (unsigned short)v0[e];
#pragma unroll
            for (int e = 0; e < 8; e++) vts[sdb + 8 + e][srow] = (unsigned short)v1[e];
        }
        // stage kr window halves
        {
            int jr = jrlo + 64 + srow;
            if (jr > RLEN - 1) jr = RLEN - 1;  // clamped row never read
            const unsigned short* krp = &krhb[((size_t)bn * RLEN + jr) * DHH + sdb];
            unsigned short* dst = &krs[(jt + 1) & 1][srow][sdb];
            *(bfx8*)dst = *(const bfx8*)krp;
            *(bfx8*)(dst + 8) = *(const bfx8*)(krp + 8);
            if (jt == 0) {
                int jr0 = jrlo + srow;  // in [1, 1024]
                const unsigned short* krp0 = &krhb[((size_t)bn * RLEN + jr0) * DHH + sdb];
                unsigned short* dst0 = &krs[0][srow][sdb];
                *(bfx8*)dst0 = *(const bfx8*)krp0;
                *(bfx8*)(dst0 + 8) = *(const bfx8*)(krp0 + 8);
            }
        }
        __syncthreads();

        // ac = qc . K^T
        f32x4 acF[4];
#pragma unroll
        for (int nf = 0; nf < 4; nf++) {
            f32x4 a = (f32x4)0.f;
#pragma unroll
            for (int kk = 0; kk < 2; kk++) {
                bfx8 kf = *(const bfx8*)&ks[nf * 16 + l15][kk * 32 + kc8];
                a = __builtin_amdgcn_mfma_f32_16x16x32_bf16(qcf[kk], kf, a, 0, 0, 0);
            }
            acF[nf] = a;
        }
        // band = qr . kr^T (5 v-frags per wave)
        f32x4 bF[5];
#pragma unroll
        for (int f = 0; f < 5; f++) {
            const int v = v0w + f * 16;
            const int bi = (jt + (v >> 6)) & 1;
            const int vr = v & 63;
            f32x4 a = (f32x4)0.f;
#pragma unroll
            for (int kk = 0; kk < 2; kk++) {
                bfx8 kf = *(const bfx8*)&krs[bi][vr + l15][kk * 32 + kc8];
                a = __builtin_amdgcn_mfma_f32_16x16x32_bf16(qrf[kk], kf, a, 0, 0, 0);
            }
            bF[f] = a;
        }

        // assemble scores (f32)
        float p[4][4];
#pragma unroll
        for (int nf = 0; nf < 4; nf++) {
#pragma unroll
            for (int q = 0; q < 4; q++) {
                const int row = rowl + q;
                const int src = (lane & 48) | ((15 - row + l15) & 15);
                float ba = __shfl(bF[nf][q], src);
                float bb = __shfl(bF[nf + 1][q], src);
                float bd = (l15 > row) ? bb : ba;
                const int gi = i0 + wave * 16 + row;
                const int gj = j0 + nf * 16 + l15;
                const unsigned char fl = flags[((size_t)gi * KLEN + gj) * BB + b];
                float sc = (acF[nf][q] + bd + efs[wave * 16 + row][fl & 1]) * SCALE;
                if (fl & 2) sc -= 1e30f;
                p[nf][q] = sc;
            }
        }

        // in-register online softmax (rows spread over 16-lane groups)
        float corr[4];
#pragma unroll
        for (int q = 0; q < 4; q++) {
            float mx = fmaxf(fmaxf(p[0][q], p[1][q]), fmaxf(p[2][q], p[3][q]));
            mx = fmaxf(mx, __shfl_xor(mx, 1));
            mx = fmaxf(mx, __shfl_xor(mx, 2));
            mx = fmaxf(mx, __shfl_xor(mx, 4));
            mx = fmaxf(mx, __shfl_xor(mx, 8));
            const float mnew = fmaxf(m_r[q], mx);
            corr[q] = __expf(m_r[q] - mnew);
            float ps = 0.f;
#pragma unroll
            for (int nf = 0; nf < 4; nf++) {
                float e = __expf(p[nf][q] - mnew);
                p[nf][q] = e;
                ps += e;
            }
            ps += __shfl_xor(ps, 1);
            ps += __shfl_xor(ps, 2);
            ps += __shfl_xor(ps, 4);
            ps += __shfl_xor(ps, 8);
            l_r[q] = l_r[q] * corr[q] + ps;
            m_r[q] = mnew;
        }
        // rescale accumulator; write P (bf16) to wave-private LDS
#pragma unroll
        for (int nf = 0; nf < 4; nf++)
#pragma unroll
            for (int q = 0; q < 4; q++) acc[nf][q] *= corr[q];
#pragma unroll
        for (int nf = 0; nf < 4; nf++)
#pragma unroll
            for (int q = 0; q < 4; q++)
                pws[wave][rowl + q][nf * 16 + l15] = f2bf(p[nf][q]);
        // PV via MFMA (A = P row-major, B = V^T)
        bfx8 pa[2];
#pragma unroll
        for (int kk = 0; kk < 2; kk++)
            pa[kk] = *(const bfx8*)&pws[wave][l15][kk * 32 + kc8];
#pragma unroll
        for (int nf = 0; nf < 4; nf++) {
#pragma unroll
            for (int kk = 0; kk < 2; kk++) {
                bfx8 vf = *(const bfx8*)&vts[nf * 16 + l15][kk * 32 + kc8];
                acc[nf] = __builtin_amdgcn_mfma_f32_16x16x32_bf16(pa[kk], vf, acc[nf], 0, 0, 0);
            }
        }
    }

    // epilogue: normalize, write bf16 attn_vec [row=(i*BB+b)][n*64+dv]
#pragma unroll
    for (int q = 0; q < 4; q++) {
        const float inv = 1.f / l_r[q];
        const int gi = i0 + wave * 16 + rowl + q;
#pragma unroll
        for (int nf = 0; nf < 4; nf++)
            avb[((size_t)gi * BB + b) * DD + n * DHH + nf * 16 + l15] =
                f2bf(acc[nf][q] * inv);
    }
}

// ---------------------------------------------------------------------------
// LayerNorm over D per (i,b) row.
// ---------------------------------------------------------------------------
__global__ __launch_bounds__(256) void k_ln(const float* __restrict__ ao,
                                            const float* __restrict__ gamma,
                                            const float* __restrict__ beta,
                                            float* __restrict__ outp) {
    const int row = blockIdx.x;
    const int t = threadIdx.x;
    float4 x = *(const float4*)&ao[(size_t)row * DD + t * 4];
    float s = x.x + x.y + x.z + x.w;
    float ss = x.x * x.x + x.y * x.y + x.z * x.z + x.w * x.w;
#pragma unroll
    for (int o = 1; o < 64; o <<= 1) {
        s += __shfl_xor(s, o);
        ss += __shfl_xor(ss, o);
    }
    __shared__ float sbuf[4], ssbuf[4];
    const int w = t >> 6;
    if ((t & 63) == 0) {
        sbuf[w] = s;
        ssbuf[w] = ss;
    }
    __syncthreads();
    s = sbuf[0] + sbuf[1] + sbuf[2] + sbuf[3];
    ss = ssbuf[0] + ssbuf[1] + ssbuf[2] + ssbuf[3];
    const float mu = s * (1.f / 1024.f);
    const float var = ss * (1.f / 1024.f) - mu * mu;
    const float rs = rsqrtf(var + 1e-12f);
    float4 g = *(const float4*)&gamma[t * 4];
    float4 bt = *(const float4*)&beta[t * 4];
    float4 o4;
    o4.x = (x.x - mu) * rs * g.x + bt.x;
    o4.y = (x.y - mu) * rs * g.y + bt.y;
    o4.z = (x.z - mu) * rs * g.z + bt.z;
    o4.w = (x.w - mu) * rs * g.w + bt.w;
    *(float4*)&outp[(size_t)row * DD + t * 4] = o4;
}

// ---------------------------------------------------------------------------
extern "C" void kernel_launch(void* const* d_in, const int* in_sizes, int n_in,
                              void* d_out, int out_size, void* d_ws, size_t ws_size,
                              hipStream_t stream) {
    (void)in_sizes; (void)n_in; (void)out_size; (void)ws_size;
    const float* h        = (const float*)d_in[0];
    const float* mems     = (const float*)d_in[1];
    const float* r        = (const float*)d_in[2];
    const float* seg_mat  = (const float*)d_in[3];
    const float* attn_mask= (const float*)d_in[4];
    const float* q_w      = (const float*)d_in[5];
    const float* k_w      = (const float*)d_in[6];
    const float* v_w      = (const float*)d_in[7];
    const float* o_w      = (const float*)d_in[8];
    const float* r_w      = (const float*)d_in[9];
    const float* r_w_bias = (const float*)d_in[10];
    const float* r_r_bias = (const float*)d_in[11];
    const float* r_s_bias = (const float*)d_in[12];
    const float* seg_embed= (const float*)d_in[13];
    const float* ln_gamma = (const float*)d_in[14];
    const float* ln_beta  = (const float*)d_in[15];
    float* outp = (float*)d_out;

    // workspace carve (all 16B aligned); total ~74 MB
    char* w = (char*)d_ws;
    unsigned short* hb  = (unsigned short*)w; w += (size_t)2097152 * 2;  // 4 MB
    unsigned short* mb  = (unsigned short*)w; w += (size_t)2097152 * 2;  // 4 MB
    unsigned short* rb  = (unsigned short*)w; w += (size_t)6291456 * 2;  // 12 MB
    unsigned short* owb = (unsigned short*)w; w += (size_t)1048576 * 2;  // 2 MB
    unsigned short* qwb = (unsigned short*)w; w += (size_t)1048576 * 2;
    unsigned short* kwb = (unsigned short*)w; w += (size_t)1048576 * 2;
    unsigned short* vwb = (unsigned short*)w; w += (size_t)1048576 * 2;
    unsigned short* rwb = (unsigned short*)w; w += (size_t)1048576 * 2;
    float* qh = (float*)w;           w += (size_t)BB * NH * QLEN * DHH * 4;  // 8 MB f32
    unsigned short* khb  = (unsigned short*)w; w += (size_t)BB * NH * KLEN * DHH * 2;  // 8 MB
    unsigned short* vhb  = (unsigned short*)w; w += (size_t)BB * NH * KLEN * DHH * 2;  // 8 MB
    unsigned short* krhb = (unsigned short*)w; w += (size_t)BB * NH * RLEN * DHH * 2;  // 12 MB
    unsigned short* avb = (unsigned short*)w; w += (size_t)2097152 * 2;  // 4 MB
    unsigned char* flags = (unsigned char*)w; w += (size_t)QLEN * KLEN * BB;  // 4 MB
    float* ao = qh;  // reuse: qh dead after k_scorepv_mfma

    k_pack<<<(QLEN * KLEN * BB) / 256, 256, 0, stream>>>(seg_mat, attn_mask, flags);
    k_cvt_all<<<5632, 256, 0, stream>>>(h, mems, r, o_w, hb, mb, rb, owb);
    k_cvtT<<<dim3(16, 16, 4), 256, 0, stream>>>(q_w, k_w, v_w, r_w, qwb, kwb, vwb, rwb);

    k_gemm<0><<<dim3(8, 8, 2), 256, 0, stream>>>(hb, hb, 1024, 2048, 1024, qwb,
                                                 nullptr, qh, QLEN);
    k_gemm<2><<<dim3(16, 8, 2), 256, 0, stream>>>(mb, hb, 1024, 2048, 1024, kwb,
                                                  nullptr, (float*)khb, KLEN);
    k_gemm<2><<<dim3(16, 8, 2), 256, 0, stream>>>(mb, hb, 1024, 2048, 1024, vwb,
                                                  nullptr, (float*)vhb, KLEN);
    k_gemm<2><<<dim3(24, 8, 2), 256, 0, stream>>>(rb, rb, 3072, 2048, 1024, rwb,
                                                  nullptr, (float*)krhb, RLEN);

    k_scorepv_mfma<<<dim3(16, 32), 256, 0, stream>>>(qh, khb, vhb, krhb, flags,
                                                     r_w_bias, r_r_bias, r_s_bias,
                                                     seg_embed, avb);

    k_gemm<1><<<dim3(16, 8, 1), 256, 0, stream>>>(avb, avb, 2048, 1024, 0, owb,
                                                  h, ao, 0);

    k_ln<<<QLEN * BB, 256, 0, stream>>>(ao, ln_gamma, ln_beta, outp);
}